// Round 5
// baseline (520.754 us; speedup 1.0000x reference)
//
#include <hip/hip_runtime.h>

#define B_ 8192
#define D_ 2048
#define E_ 16
#define P_ 1024

typedef unsigned int u32;
typedef __attribute__((ext_vector_type(8)))  short bf16x8;
typedef __attribute__((ext_vector_type(16))) float f32x16;

__device__ __forceinline__ float dot4(float4 a, float4 b) {
  return a.x*b.x + a.y*b.y + a.z*b.z + a.w*b.w;
}

// fp32 -> bf16 hi/lo truncation split (v = hi + lo, exact to 16 mantissa bits).
// hi-pack of (a,b) via v_perm_b32: result = (ua>>16) | (ub & 0xFFFF0000).
__device__ __forceinline__ void split2(float a, float b, u32& h, u32& l) {
  u32 ua = __float_as_uint(a), ub = __float_as_uint(b);
  h = __builtin_amdgcn_perm(ub, ua, 0x07060302u);
  float la = a - __uint_as_float(ua & 0xFFFF0000u);
  float lb = b - __uint_as_float(ub & 0xFFFF0000u);
  l = __builtin_amdgcn_perm(__float_as_uint(lb), __float_as_uint(la), 0x07060302u);
}
__device__ __forceinline__ void split8(float4 f0, float4 f1, uint4& hi, uint4& lo) {
  split2(f0.x, f0.y, hi.x, lo.x);
  split2(f0.z, f0.w, hi.y, lo.y);
  split2(f1.x, f1.y, hi.z, lo.z);
  split2(f1.z, f1.w, hi.w, lo.w);
}

__device__ __forceinline__ f32x16 mfma32(uint4 a, uint4 b, f32x16 c) {
  return __builtin_amdgcn_mfma_f32_32x32x16_bf16(
      __builtin_bit_cast(bf16x8, a), __builtin_bit_cast(bf16x8, b), c, 0, 0, 0);
}

__global__ void k_zero(int* __restrict__ counts) {
  if (threadIdx.x < 16) counts[threadIdx.x] = 0;
}

// ============ parent (exact fp32) + fused parent_proj ============
// 256 blocks x 512 threads; 32 rows/block. fc: LDS-staged weights, 4 rows/wave.
// pproj fused: each thread owns 2 wp rows in regs; pl broadcast from LDS.
__global__ __launch_bounds__(512) void k_parent(
    const float* __restrict__ x, const float* __restrict__ wfc,
    const float* __restrict__ bfc, const float* __restrict__ wp,
    const float* __restrict__ bp, float* __restrict__ out_pl,
    float* __restrict__ out_pp, int* __restrict__ cls, int* __restrict__ counts)
{
  __shared__ float wl[16 * 512];
  __shared__ float pl_lds[32][20];     // stride 20 f32 = 80 B (16B-aligned rows)
  const int tid  = threadIdx.x;
  const int wave = tid >> 6, lane = tid & 63;
  const int row0 = blockIdx.x * 32 + wave * 4;

  // pproj weights: thread owns wp rows p0, p0+1 (32 f32 in regs)
  const int p0 = tid * 2;
  float4 wq[8];
  #pragma unroll
  for (int q = 0; q < 8; ++q) wq[q] = ((const float4*)(wp + p0 * 16))[q];
  const float bq0 = bp[p0], bq1 = bp[p0 + 1];

  float acc[4][16];
  #pragma unroll
  for (int r = 0; r < 4; ++r)
    #pragma unroll
    for (int e = 0; e < 16; ++e) acc[r][e] = 0.f;

  for (int ch = 0; ch < 4; ++ch) {            // 4 chunks of 512 over D
    __syncthreads();
    #pragma unroll
    for (int it = 0; it < 4; ++it) {
      int i = tid * 4 + it * 2048;
      int e = i >> 9, k = i & 511;
      *(float4*)&wl[i] = *(const float4*)&wfc[e * 2048 + ch * 512 + k];
    }
    __syncthreads();
    float4 xv[4][2];
    #pragma unroll
    for (int r = 0; r < 4; ++r) {
      const float* xr = x + (size_t)(row0 + r) * D_ + ch * 512;
      xv[r][0] = *(const float4*)&xr[lane * 4];
      xv[r][1] = *(const float4*)&xr[lane * 4 + 256];
    }
    #pragma unroll
    for (int e = 0; e < 16; ++e) {
      float4 w0 = *(const float4*)&wl[e * 512 + lane * 4];
      float4 w1 = *(const float4*)&wl[e * 512 + lane * 4 + 256];
      #pragma unroll
      for (int r = 0; r < 4; ++r)
        acc[r][e] += dot4(xv[r][0], w0) + dot4(xv[r][1], w1);
    }
  }
  #pragma unroll
  for (int r = 0; r < 4; ++r)
    #pragma unroll
    for (int e = 0; e < 16; ++e) {
      float v = acc[r][e];
      #pragma unroll
      for (int m = 32; m >= 1; m >>= 1) v += __shfl_xor(v, m, 64);
      acc[r][e] = v;
    }
  if (lane < 4) {                             // lane r handles row row0+r
    const int r = lane;
    const int row = row0 + r;
    float z[16]; float s = 0.f;
    #pragma unroll
    for (int e = 0; e < 16; ++e) { z[e] = acc[r][e] + bfc[e]; s += z[e]; }
    const float mu = s * (1.f / 16.f);
    float s2 = 0.f;
    #pragma unroll
    for (int e = 0; e < 16; ++e) { float d = z[e] - mu; s2 += d * d; }
    const float rstd = rsqrtf(s2 * (1.f / 16.f) + 1e-5f);
    int best = 0; float bv = z[0];
    #pragma unroll
    for (int e = 1; e < 16; ++e) if (z[e] > bv) { bv = z[e]; best = e; }
    #pragma unroll
    for (int e = 0; e < 16; ++e) {
      const float zn = (z[e] - mu) * rstd;
      out_pl[(size_t)row * 16 + e] = zn;
      pl_lds[wave * 4 + r][e] = zn;
    }
    cls[row] = best;
    atomicAdd(&counts[best], 1);
  }
  __syncthreads();
  // pproj: out_pp[row][p] = dot16(pl[row], wp[p]) + bp[p]
  #pragma unroll 4
  for (int r = 0; r < 32; ++r) {
    float4 a0 = *(const float4*)&pl_lds[r][0];
    float4 a1 = *(const float4*)&pl_lds[r][4];
    float4 a2 = *(const float4*)&pl_lds[r][8];
    float4 a3 = *(const float4*)&pl_lds[r][12];
    float o0 = dot4(a0, wq[0]) + dot4(a1, wq[1]) + dot4(a2, wq[2]) + dot4(a3, wq[3]) + bq0;
    float o1 = dot4(a0, wq[4]) + dot4(a1, wq[5]) + dot4(a2, wq[6]) + dot4(a3, wq[7]) + bq1;
    float2 ov = {o0, o1};
    *(float2*)&out_pp[(size_t)(blockIdx.x * 32 + r) * 1024 + p0] = ov;
  }
}

__global__ void k_scan(const int* __restrict__ counts,
                       int* __restrict__ starts, int* __restrict__ cursor) {
  if (threadIdx.x == 0) {
    int run = 0;
    for (int e = 0; e < 16; ++e) { starts[e] = run; cursor[e] = run; run += counts[e]; }
  }
}

__global__ __launch_bounds__(256) void k_scatter(
    const int* __restrict__ cls, int* __restrict__ cursor, int* __restrict__ idxb) {
  const int b = blockIdx.x * 256 + threadIdx.x;
  const int c = cls[b];
  const int pos = atomicAdd(&cursor[c], 1);
  idxb[pos] = b;
}

// ============ fused child level: zero-LDS-staging split-bf16 MFMA ============
// 64-row tiles, 4 waves. fc: K-split-4 (wave = K quarter), each wave computes the
// FULL 64xC tile for its K range; operands gathered global->reg in 32x32x16
// fragment layout (lane l: idx l&31, k-oct l>>5), split hi/lo in-reg.
// frag maps (m74/m101): A row=l&31,k=(l>>5)*8+i ; B col=l&31,same k ;
//                       C/D col=l&31, row=(r&3)+8*(r>>2)+4*(l>>5), r=reg 0..15.
// LDS: red4 rounds (48KB max) then hbuf[64][C+4] f32 (34KB max), reused region.
template<int C>
__device__ __forceinline__ void child_body(
    char* smem, int* rid_s,
    const float* __restrict__ x, const float* __restrict__ wfc,
    const float* __restrict__ bfc, const float* __restrict__ wpj,
    const float* __restrict__ bpj, const int* __restrict__ starts,
    const int* __restrict__ counts, const int* __restrict__ idxb,
    float* __restrict__ out_cl, float* __restrict__ out_cp,
    const int e, const int t)
{
  constexpr int NFR = C / 32;     // fc n-frags (2|4)
  constexpr int KS  = C / 16;     // proj K16 steps (4|8)
  const int tid = threadIdx.x;
  const int lane = tid & 63, wave = tid >> 6;
  const int l31 = lane & 31, lh = lane >> 5;

  const int n = counts[e];
  const int r0 = t * 64;
  if (r0 >= n) return;
  const int rows = min(64, n - r0);
  const int st = starts[e];
  if (tid < 64) rid_s[tid] = idxb[st + r0 + min(tid, rows - 1)];
  __syncthreads();

  // ---------------- fc: z[64][C] = X[64][2048] @ Wfc[C][2048]^T ----------------
  const float* xa0 = x + (size_t)rid_s[l31] * D_ + lh * 8;
  const float* xa1 = x + (size_t)rid_s[32 + l31] * D_ + lh * 8;
  const float* wa[NFR];
  #pragma unroll
  for (int nf = 0; nf < NFR; ++nf)
    wa[nf] = wfc + (size_t)(e * C + nf * 32 + l31) * D_ + lh * 8;

  f32x16 acc[2][NFR];
  #pragma unroll
  for (int mf = 0; mf < 2; ++mf)
    #pragma unroll
    for (int nf = 0; nf < NFR; ++nf)
      #pragma unroll
      for (int r = 0; r < 16; ++r) acc[mf][nf][r] = 0.f;

  const int kbase = wave << 9;                 // this wave's K quarter
  for (int s = 0; s < 32; ++s) {
    const int k0 = kbase + (s << 4);
    uint4 xh[2], xl[2], wh[NFR], wlo[NFR];
    {
      float4 f0 = *(const float4*)(xa0 + k0);
      float4 f1 = *(const float4*)(xa0 + k0 + 4);
      split8(f0, f1, xh[0], xl[0]);
      f0 = *(const float4*)(xa1 + k0);
      f1 = *(const float4*)(xa1 + k0 + 4);
      split8(f0, f1, xh[1], xl[1]);
    }
    #pragma unroll
    for (int nf = 0; nf < NFR; ++nf) {
      float4 f0 = *(const float4*)(wa[nf] + k0);
      float4 f1 = *(const float4*)(wa[nf] + k0 + 4);
      split8(f0, f1, wh[nf], wlo[nf]);
    }
    #pragma unroll
    for (int nf = 0; nf < NFR; ++nf)
      #pragma unroll
      for (int mf = 0; mf < 2; ++mf) {
        acc[mf][nf] = mfma32(xh[mf], wh[nf],  acc[mf][nf]);
        acc[mf][nf] = mfma32(xh[mf], wlo[nf], acc[mf][nf]);
        acc[mf][nf] = mfma32(xl[mf], wh[nf],  acc[mf][nf]);
      }
  }

  // ---------------- K-split reduction (2 rounds, owner wave mf) ----------------
  uint4* red4 = (uint4*)smem;
  #pragma unroll
  for (int mf = 0; mf < 2; ++mf) {
    __syncthreads();
    if (wave != mf) {
      const int sw = (wave < mf) ? wave : wave - 1;    // writer slot 0..2
      #pragma unroll
      for (int nf = 0; nf < NFR; ++nf)
        #pragma unroll
        for (int q = 0; q < 4; ++q) {
          uint4 v;
          v.x = __float_as_uint(acc[mf][nf][4 * q + 0]);
          v.y = __float_as_uint(acc[mf][nf][4 * q + 1]);
          v.z = __float_as_uint(acc[mf][nf][4 * q + 2]);
          v.w = __float_as_uint(acc[mf][nf][4 * q + 3]);
          red4[((nf * 4 + q) * 3 + sw) * 64 + lane] = v;
        }
    }
    __syncthreads();
    if (wave == mf) {
      #pragma unroll
      for (int nf = 0; nf < NFR; ++nf)
        #pragma unroll
        for (int q = 0; q < 4; ++q)
          #pragma unroll
          for (int sw = 0; sw < 3; ++sw) {
            uint4 v = red4[((nf * 4 + q) * 3 + sw) * 64 + lane];
            acc[mf][nf][4 * q + 0] += __uint_as_float(v.x);
            acc[mf][nf][4 * q + 1] += __uint_as_float(v.y);
            acc[mf][nf][4 * q + 2] += __uint_as_float(v.z);
            acc[mf][nf][4 * q + 3] += __uint_as_float(v.w);
          }
    }
  }
  __syncthreads();

  // ---------------- bias + LayerNorm (owner waves 0,1), cl store, h -> LDS ----
  float* hbuf = (float*)smem;                  // [64][C+4] f32, reuses red region
  if (wave < 2) {
    const int mf = wave;
    float h[NFR][16];
    #pragma unroll
    for (int nf = 0; nf < NFR; ++nf) {
      const float bias = bfc[e * C + nf * 32 + l31];
      #pragma unroll
      for (int r = 0; r < 16; ++r) h[nf][r] = acc[mf][nf][r] + bias;
    }
    #pragma unroll
    for (int r = 0; r < 16; ++r) {
      float sv = 0.f, qv = 0.f;
      #pragma unroll
      for (int nf = 0; nf < NFR; ++nf) { sv += h[nf][r]; qv += h[nf][r] * h[nf][r]; }
      #pragma unroll
      for (int m = 1; m < 32; m <<= 1) { sv += __shfl_xor(sv, m, 64); qv += __shfl_xor(qv, m, 64); }
      const float mu = sv * (1.f / C);
      const float var = qv * (1.f / C) - mu * mu;
      const float rstd = rsqrtf(var + 1e-5f);
      const int row_l = mf * 32 + (r & 3) + 8 * (r >> 2) + 4 * lh;
      const bool valid = row_l < rows;
      const int rid = rid_s[row_l];
      #pragma unroll
      for (int nf = 0; nf < NFR; ++nf) {
        const float hn = (h[nf][r] - mu) * rstd;
        h[nf][r] = hn;
        if (valid) out_cl[(size_t)rid * C + nf * 32 + l31] = hn;
        hbuf[row_l * (C + 4) + nf * 32 + l31] = hn;
      }
    }
  }
  __syncthreads();

  // ---------------- proj A-fragments from hbuf (all waves) ----------------
  uint4 pah[2][KS], pal[2][KS];
  #pragma unroll
  for (int mf = 0; mf < 2; ++mf)
    #pragma unroll
    for (int ks = 0; ks < KS; ++ks) {
      const float* hp = hbuf + (mf * 32 + l31) * (C + 4) + ks * 16 + lh * 8;
      float4 f0 = *(const float4*)hp;
      float4 f1 = *(const float4*)(hp + 4);
      split8(f0, f1, pah[mf][ks], pal[mf][ks]);
    }

  // ---------------- proj: out_cp[64][1024] = h[64][C] @ Wp[1024][C]^T ---------
  #pragma unroll 1
  for (int j = 0; j < 8; ++j) {
    const int nfg = wave * 8 + j;
    const float* wb = wpj + (size_t)(e * 1024 + nfg * 32 + l31) * C + lh * 8;
    f32x16 p[2];
    #pragma unroll
    for (int mf = 0; mf < 2; ++mf)
      #pragma unroll
      for (int r = 0; r < 16; ++r) p[mf][r] = 0.f;
    #pragma unroll
    for (int ks = 0; ks < KS; ++ks) {
      float4 f0 = *(const float4*)(wb + ks * 16);
      float4 f1 = *(const float4*)(wb + ks * 16 + 4);
      uint4 wh, wlo;
      split8(f0, f1, wh, wlo);
      #pragma unroll
      for (int mf = 0; mf < 2; ++mf) {
        p[mf] = mfma32(pah[mf][ks], wh,  p[mf]);
        p[mf] = mfma32(pah[mf][ks], wlo, p[mf]);
        p[mf] = mfma32(pal[mf][ks], wh,  p[mf]);
      }
    }
    const float bias = bpj[e * 1024 + nfg * 32 + l31];
    #pragma unroll
    for (int mf = 0; mf < 2; ++mf)
      #pragma unroll
      for (int r = 0; r < 16; ++r) {
        const int row_l = mf * 32 + (r & 3) + 8 * (r >> 2) + 4 * lh;
        if (row_l < rows)
          out_cp[(size_t)rid_s[row_l] * 1024 + nfg * 32 + l31] = p[mf][r] + bias;
      }
  }
}

// merged launch: both child levels, e in low 4 bits (2 experts per XCD => weights
// L2-resident per chiplet). 16e x 2lvl x 128 tiles = 4096 blocks, most exit fast.
__global__ __launch_bounds__(256, 1) void k_child_both(
    const float* __restrict__ x,
    const float* __restrict__ wfc0, const float* __restrict__ bfc0,
    const float* __restrict__ wpj0, const float* __restrict__ bpj0,
    const float* __restrict__ wfc1, const float* __restrict__ bfc1,
    const float* __restrict__ wpj1, const float* __restrict__ bpj1,
    const int* __restrict__ starts, const int* __restrict__ counts,
    const int* __restrict__ idxb,
    float* __restrict__ out_cl0, float* __restrict__ out_cp0,
    float* __restrict__ out_cl1, float* __restrict__ out_cp1)
{
  __shared__ __align__(16) char smem[49152];
  __shared__ int rid_s[64];
  const int e = blockIdx.x & 15;
  const int rest = blockIdx.x >> 4;
  const int lvl = rest & 1;
  const int t = rest >> 1;
  if (lvl == 0)
    child_body<64>(smem, rid_s, x, wfc0, bfc0, wpj0, bpj0,
                   starts, counts, idxb, out_cl0, out_cp0, e, t);
  else
    child_body<128>(smem, rid_s, x, wfc1, bfc1, wpj1, bpj1,
                    starts, counts, idxb, out_cl1, out_cp1, e, t);
}

extern "C" void kernel_launch(void* const* d_in, const int* in_sizes, int n_in,
                              void* d_out, int out_size, void* d_ws, size_t ws_size,
                              hipStream_t stream)
{
  (void)in_sizes; (void)n_in; (void)out_size; (void)ws_size;
  const float* x       = (const float*)d_in[0];
  const float* pw_fc   = (const float*)d_in[1];
  const float* pb_fc   = (const float*)d_in[2];
  const float* pw_proj = (const float*)d_in[3];
  const float* pb_proj = (const float*)d_in[4];
  const float* cw_fc0  = (const float*)d_in[5];
  const float* cb_fc0  = (const float*)d_in[6];
  const float* cw_pj0  = (const float*)d_in[7];
  const float* cb_pj0  = (const float*)d_in[8];
  const float* cw_fc1  = (const float*)d_in[9];
  const float* cb_fc1  = (const float*)d_in[10];
  const float* cw_pj1  = (const float*)d_in[11];
  const float* cb_pj1  = (const float*)d_in[12];

  float* out = (float*)d_out;
  float* out_pl  = out;                                   // [B,16]
  float* out_cl0 = out_pl  + (size_t)B_ * 16;             // [B,64]
  float* out_cl1 = out_cl0 + (size_t)B_ * 64;             // [B,128]
  float* out_pp  = out_cl1 + (size_t)B_ * 128;            // [B,1024]
  float* out_cp0 = out_pp  + (size_t)B_ * 1024;           // [B,1024]
  float* out_cp1 = out_cp0 + (size_t)B_ * 1024;           // [B,1024]

  int* cls    = (int*)d_ws;       // [B]
  int* idxb   = cls + B_;         // [B]
  int* counts = idxb + B_;        // [16]
  int* starts = counts + 16;      // [16]
  int* cursor = starts + 16;      // [16]

  k_zero<<<1, 64, 0, stream>>>(counts);
  k_parent<<<256, 512, 0, stream>>>(x, pw_fc, pb_fc, pw_proj, pb_proj,
                                    out_pl, out_pp, cls, counts);
  k_scan<<<1, 64, 0, stream>>>(counts, starts, cursor);
  k_scatter<<<B_ / 256, 256, 0, stream>>>(cls, cursor, idxb);
  k_child_both<<<4096, 256, 0, stream>>>(
      x, cw_fc0, cb_fc0, cw_pj0, cb_pj0, cw_fc1, cb_fc1, cw_pj1, cb_pj1,
      starts, counts, idxb, out_cl0, out_cp0, out_cl1, out_cp1);
}